// Round 12
// baseline (1664.199 us; speedup 1.0000x reference)
//
#include <hip/hip_runtime.h>
#include <stdint.h>
#include <stddef.h>

// ---------------------------------------------------------------------------
// PCgraph: T=32 steps of
//   mu = tanh(x) @ w^T ; e = (x-mu)*m ; g = e @ w ;
//   x = x - 0.1*m*(e - (1-tanh(x)^2)*g)
// bf16 MFMA 16x16x32, fp32 accum. x state in d_out (fp32).
// Round 12: SQUARE 128x128 tile, BK=32, Z=8 (grid 416). Model after r9/r11:
// per-CU LDS-DMA fill saturates at ~19-22 B/cyc/CU; bytes ~ (1/BM+1/BN) are
// the lever, but only if the staging shape (4 x 1KB-linear DMA per wave per
// iter, r9's proven MLP) is preserved. 128x128 halves bytes vs r9
// (213->106 MB GEMM1) at identical staging shape; 32 KB LDS keeps 5
// blocks/CU LDS-cap; ~130 VGPR caps at 3 (avg residency 1.6). Straggler
// check: 2-block CUs 512KB @ ~20 B/cyc ~ 10.7us vs 1-block 256KB @ ~12
// ~ 8.9us -- balanced. Z=8 partials / cvt / pack / ws unchanged
// (end 66,846,720 B proven by r10/r11; ws likely exactly 64 MiB).
// ---------------------------------------------------------------------------

#define N_DIM 4096
#define B_DIM 256
#define T_STEPS 32
#define LR_X 0.1f
#define N0 768                      // first live column (aligned down from 784)
#define N_LIVE 3328                 // 4096 - 768 = 52*64

#define NCH1 64                     // 64-wide k-chunks in GEMM1 (k over 4096)
#define NCH2 52                     // k-chunks in GEMM2 (k over 3328)

typedef unsigned short ushort_t;
using bf16x8 = __attribute__((ext_vector_type(8))) __bf16;
using f32x4  = __attribute__((ext_vector_type(4))) float;

__device__ __forceinline__ ushort_t f2bf(float f) {
    union { float f; unsigned int u; } v; v.f = f;
    unsigned int r = v.u + 0x7fffu + ((v.u >> 16) & 1u);   // RNE
    return (ushort_t)(r >> 16);
}
__device__ __forceinline__ float bf2f(ushort_t h) {
    union { unsigned int u; float f; } v; v.u = ((unsigned int)h) << 16;
    return v.f;
}

// fragment-order index of element (r, c) inside a 64x64 tile-chunk
__device__ __forceinline__ int pkidx(int r, int c) {
    const int s = ((r >> 4) << 1) | ((c >> 5) & 1);
    return s * 512 + (r & 15) * 8 + (((c >> 3) & 3) << 7) + (c & 7);
}

__device__ __forceinline__ void async_copy16(const ushort_t* g, ushort_t* l) {
    __builtin_amdgcn_global_load_lds(
        (__attribute__((address_space(1))) void*)(g),
        (__attribute__((address_space(3))) void*)(l),
        16, 0, 0);
}

// --- pack w -> w_pk [52 ntile][64 chunk][4096]  (B of GEMM1: rows 768..4095)
//            -> wt_pk [52 ntile][52 chunk][4096] (B of GEMM2: w^T, live range)
__global__ __launch_bounds__(256) void pack_w(const float* __restrict__ w,
                                              ushort_t* __restrict__ wpk,
                                              ushort_t* __restrict__ wtpk) {
    __shared__ float tile[64][68];
    const int tid = threadIdx.x;
    const int bid = blockIdx.x;
    int row0, col0; ushort_t* dst; bool tr;
    if (bid < 52 * 64) {
        tr   = false;
        dst  = wpk + (size_t)bid * 4096;
        row0 = N0 + (bid >> 6) * 64;      // B-row (n) block
        col0 = (bid & 63) * 64;           // k block
    } else {
        const int b2 = bid - 52 * 64;
        tr   = true;
        dst  = wtpk + (size_t)b2 * 4096;
        const int ntile = b2 / 52, chunk = b2 - ntile * 52;
        row0 = N0 + chunk * 64;           // w-row  = k block (live)
        col0 = N0 + ntile * 64;           // w-col  = n block (live)
    }
    const int rr = tid >> 2, c0 = (tid & 3) * 16;
    const float* src = w + (size_t)(row0 + rr) * N_DIM + col0 + c0;
#pragma unroll
    for (int i = 0; i < 16; i += 4)
        *(float4*)&tile[rr][c0 + i] = *(const float4*)(src + i);
    __syncthreads();
    ushort_t loc[16];
#pragma unroll
    for (int i = 0; i < 16; ++i) {
        const int p = tid * 16 + i;
        const int s = p >> 9, e = p & 511;
        const int r = ((s >> 1) << 4) | ((e >> 3) & 15);
        const int c = ((s & 1) << 5) | (((e >> 7) & 3) << 3) | (e & 7);
        loc[i] = f2bf(tr ? tile[c][r] : tile[r][c]);
    }
    *(uint4*)&dst[tid * 16]     = *(uint4*)&loc[0];
    *(uint4*)&dst[tid * 16 + 8] = *(uint4*)&loc[8];
}

// --- init: x -> d_out (row-major) and t_pk [4 mtile][64 chunk][4096] --------
__global__ __launch_bounds__(256) void pack_t_init(const float* __restrict__ xin,
                                                   float* __restrict__ xout,
                                                   ushort_t* __restrict__ tpk) {
    __shared__ float tile[64][68];
    const int tid  = threadIdx.x;
    const int bid  = blockIdx.x;          // mtile*64 + chunk
    const int row0 = (bid >> 6) * 64;
    const int col0 = (bid & 63) * 64;
    const int rr = tid >> 2, c0 = (tid & 3) * 16;
    const size_t sidx = (size_t)(row0 + rr) * N_DIM + col0 + c0;
#pragma unroll
    for (int i = 0; i < 16; i += 4) {
        float4 v = *(const float4*)(xin + sidx + i);
        *(float4*)(xout + sidx + i) = v;
        tile[rr][c0 + i + 0] = tanhf(v.x);
        tile[rr][c0 + i + 1] = tanhf(v.y);
        tile[rr][c0 + i + 2] = tanhf(v.z);
        tile[rr][c0 + i + 3] = tanhf(v.w);
    }
    __syncthreads();
    ushort_t loc[16];
    ushort_t* dst = tpk + (size_t)bid * 4096;
#pragma unroll
    for (int i = 0; i < 16; ++i) {
        const int p = tid * 16 + i;
        const int s = p >> 9, e = p & 511;
        const int r = ((s >> 1) << 4) | ((e >> 3) & 15);
        const int c = ((s & 1) << 5) | (((e >> 7) & 3) << 3) | (e & 7);
        loc[i] = f2bf(tile[r][c]);
    }
    *(uint4*)&dst[tid * 16]     = *(uint4*)&loc[0];
    *(uint4*)&dst[tid * 16 + 8] = *(uint4*)&loc[8];
}

// --- cvt1 (after GEMM1): mu = sum partials; e -> e_pk (packed, GEMM2 A) -----
__global__ void cvt1(const float* __restrict__ xbuf,
                     const ushort_t* __restrict__ part,
                     ushort_t* __restrict__ epk,
                     const int* __restrict__ mask, int nz) {
    const int b  = blockIdx.y;
    const int nl = blockIdx.x * 256 + threadIdx.x;
    const size_t il = (size_t)b * N_LIVE + nl;
    float mu = 0.0f;
    for (int z = 0; z < nz; ++z)
        mu += bf2f(part[(size_t)z * (B_DIM * N_LIVE) + il]);
    const float x = xbuf[(size_t)b * N_DIM + N0 + nl];
    const float e = (x - mu) * (float)mask[N0 + nl];
    epk[((size_t)((b >> 6) * NCH2 + (nl >> 6))) * 4096 + pkidx(b & 63, nl & 63)]
        = f2bf(e);
}

// --- cvt2 (after GEMM2): g = sum partials; x update; refresh t_pk -----------
__global__ void cvt2(float* __restrict__ xbuf,
                     const ushort_t* __restrict__ part,
                     const ushort_t* __restrict__ epk,
                     ushort_t* __restrict__ tpk,
                     const int* __restrict__ mask, int nz) {
    const int b  = blockIdx.y;
    const int nl = blockIdx.x * 256 + threadIdx.x;
    const size_t ix = (size_t)b * N_DIM + N0 + nl;
    float g = 0.0f;
    for (int z = 0; z < nz; ++z)
        g += bf2f(part[(size_t)z * (B_DIM * N_LIVE) + (size_t)b * N_LIVE + nl]);
    const float x  = xbuf[ix];
    const float th = tanhf(x);
    const float e  = bf2f(epk[((size_t)((b >> 6) * NCH2 + (nl >> 6))) * 4096
                              + pkidx(b & 63, nl & 63)]);
    const float m  = (float)mask[N0 + nl];
    const float xn = x - LR_X * m * (e - (1.0f - th * th) * g);
    xbuf[ix] = xn;
    const int k = N0 + nl;
    tpk[((size_t)((b >> 6) * NCH1 + (k >> 6))) * 4096 + pkidx(b & 63, k & 63)]
        = f2bf(tanhf(xn));
}

// --- split-K GEMM, 128x128 tile / BK=32, 32 KB LDS --------------------------
// grid (26, 2, Z). K in 32-wide halves: NH = 2*NCH (128 / 104), NH % Z == 0
// for Z in {4, 8}. A = packed mtiles {2y, 2y+1}; B = packed ntiles {2x, 2x+1}.
// Sub-tile st = p*4 + g2 (p = which 64-row half, g2 = 16-row group); each
// wave stages 2 A + 2 B sub-tiles = 4 x 1KB lane-linear DMAs (r9's shape).
// Each wave computes a 64x64 output quadrant: 16 MFMA per iter.
template <int NCH>
__global__ __launch_bounds__(256) void gemm_split(
    const ushort_t* __restrict__ Apk,
    const ushort_t* __restrict__ Bpk,
    ushort_t* __restrict__ part, int Z) {
    __shared__ __align__(16) ushort_t As[2][8 * 512];   // 2 x 8 KB
    __shared__ __align__(16) ushort_t Bs[2][8 * 512];   // 2 x 8 KB

    const int tid    = threadIdx.x;
    const int lane   = tid & 63;
    const int wid    = tid >> 6;       // 0..3
    const int wave_m = wid >> 1;       // 0..1  (64-row half of 128)
    const int wave_n = wid & 1;        // 0..1  (64-col half of 128)
    const int ntile2 = blockIdx.x;     // covers ntiles {2x, 2x+1}
    const int mtile2 = blockIdx.y;     // covers mtiles {2y, 2y+1}
    const int z      = blockIdx.z;

    const int NH  = 2 * NCH;
    const int per = NH / Z;            // 16 / 13 (Z=8)
    const int h0  = z * per;
    ushort_t* pout = part + (size_t)z * (B_DIM * N_LIVE);

    const int l15  = lane & 15;
    const int quad = lane >> 4;        // 0..3

    const ushort_t* Ab0 = Apk + (size_t)(mtile2 * 2) * NCH * 4096;
    const ushort_t* Ab1 = Ab0 + (size_t)NCH * 4096;
    const ushort_t* Bb0 = Bpk + (size_t)(ntile2 * 2) * NCH * 4096;
    const ushort_t* Bb1 = Bb0 + (size_t)NCH * 4096;

    auto stage = [&](int buf, int h) {
        const size_t co = (size_t)(h >> 1) * 4096;   // chunk offset
        const int hh = h & 1;                        // k-half within chunk
#pragma unroll
        for (int u = 0; u < 2; ++u) {
            const int st = wid * 2 + u;              // 0..7 = p*4 + g2
            const int p  = st >> 2, g2 = st & 3;
            const int so = (g2 * 2 + hh) * 512 + lane * 8;
            const int dо = st * 512 + lane * 8;
            async_copy16((p ? Ab1 : Ab0) + co + so, &As[buf][dо]);
            async_copy16((p ? Bb1 : Bb0) + co + so, &Bs[buf][dо]);
        }
    };

    f32x4 acc[4][4] = {};

    auto compute = [&](int buf) {
        bf16x8 a[4], b[4];
#pragma unroll
        for (int i = 0; i < 4; ++i)
            a[i] = *(const bf16x8*)(&As[buf][(wave_m * 4 + i) * 512 + lane * 8]);
#pragma unroll
        for (int j = 0; j < 4; ++j)
            b[j] = *(const bf16x8*)(&Bs[buf][(wave_n * 4 + j) * 512 + lane * 8]);
#pragma unroll
        for (int i = 0; i < 4; ++i)
#pragma unroll
            for (int j = 0; j < 4; ++j)
                acc[i][j] = __builtin_amdgcn_mfma_f32_16x16x32_bf16(
                    a[i], b[j], acc[i][j], 0, 0, 0);
    };

    stage(0, h0);
    __syncthreads();
    for (int it = 0; it < per; ++it) {
        if (it + 1 < per) stage((it + 1) & 1, h0 + it + 1);
        compute(it & 1);
        __syncthreads();
    }

    // Epilogue: bf16 partial stores. C/D: col = lane&15, row = quad*4+reg
#pragma unroll
    for (int j = 0; j < 4; ++j) {
        const int nl = ntile2 * 128 + wave_n * 64 + j * 16 + l15;
#pragma unroll
        for (int i = 0; i < 4; ++i) {
#pragma unroll
            for (int r = 0; r < 4; ++r) {
                const int m = mtile2 * 128 + wave_m * 64 + i * 16 + quad * 4 + r;
                pout[(size_t)m * N_LIVE + nl] = f2bf(acc[i][j][r]);
            }
        }
    }
}

extern "C" void kernel_launch(void* const* d_in, const int* in_sizes, int n_in,
                              void* d_out, int out_size, void* d_ws, size_t ws_size,
                              hipStream_t stream) {
    const float* x_in  = (const float*)d_in[0];
    const float* w_in  = (const float*)d_in[1];
    const int*   mask  = (const int*)d_in[2];
    float*       xbuf  = (float*)d_out;          // state lives in d_out

    uint8_t* ws = (uint8_t*)d_ws;
    ushort_t* w_pk  = (ushort_t*)(ws);                   // 52*64*4096*2 = 27,262,976
    ushort_t* wt_pk = (ushort_t*)(ws + 27262976);        // 52*52*4096*2 = 22,151,168
    ushort_t* t_pk  = (ushort_t*)(ws + 49414144);        //  4*64*4096*2 =  2,097,152
    ushort_t* e_pk  = (ushort_t*)(ws + 51511296);        //  4*52*4096*2 =  1,703,936
    ushort_t* part  = (ushort_t*)(ws + 53215232);        // Z*256*3328*2

    // Z=8 end @ 66,846,720 bytes (proven in-bounds by rounds 10/11).
    const int Z = (ws_size >= (size_t)66846720) ? 8 : 4;

    pack_w<<<dim3(52 * 64 + 52 * 52), 256, 0, stream>>>(w_in, w_pk, wt_pk);
    pack_t_init<<<dim3(4 * 64), 256, 0, stream>>>(x_in, xbuf, t_pk);

    const dim3 ggrid(N_LIVE / 128, B_DIM / 128, Z);
    const dim3 cgrid(N_LIVE / 256, B_DIM);
    for (int t = 0; t < T_STEPS; ++t) {
        // GEMM1: part[z] = mu partial ; A = t_pk (128 halves), B = w_pk
        gemm_split<NCH1><<<ggrid, 256, 0, stream>>>(t_pk, w_pk, part, Z);
        cvt1<<<cgrid, 256, 0, stream>>>(xbuf, part, e_pk, mask, Z);
        // GEMM2: part[z] = g partial ; A = e_pk (104 halves), B = wt_pk
        gemm_split<NCH2><<<ggrid, 256, 0, stream>>>(e_pk, wt_pk, part, Z);
        cvt2<<<cgrid, 256, 0, stream>>>(xbuf, part, e_pk, t_pk, mask, Z);
    }
}

// Round 13
// 1620.681 us; speedup vs baseline: 1.0269x; 1.0269x over previous
//
#include <hip/hip_runtime.h>
#include <stdint.h>
#include <stddef.h>

// ---------------------------------------------------------------------------
// PCgraph: T=32 steps of
//   mu = tanh(x) @ w^T ; e = (x-mu)*m ; g = e @ w ;
//   x = x - 0.1*m*(e - (1-tanh(x)^2)*g)
// bf16 MFMA 16x16x32, fp32 accum. x state in d_out (fp32).
// Round 13: 128x128 tile, BK=64 (one full packed chunk per iter) -> 8 iters
// per z-slice. Unified timing model from r2/r6/r9/r11/r12:
//   dispatch ~= iters x max(~2800cyc drain latency, CU-bytes/iter / ~19B/cyc)
// r9 was fill-bound (52KB/CU/iter at crossover); r12 latency-bound (16 iters,
// 26KB/CU/iter). Nobody reduced iters below 16 before. At 8 iters x 32KB/blk
// the latency floor (22.4k cyc) meets the byte floor (21.8k cyc) -- the
// structural optimum. LDS 64KB dbuf (2 blk/CU cap, grid 416 -> 1.6 avg).
// Staging: 8 x 1KB-linear DMAs/wave/iter. Z=8 partials (ws end 66,846,720 B
// proven by r10-r12; ws is almost surely exactly 64 MiB).
// ---------------------------------------------------------------------------

#define N_DIM 4096
#define B_DIM 256
#define T_STEPS 32
#define LR_X 0.1f
#define N0 768                      // first live column (aligned down from 784)
#define N_LIVE 3328                 // 4096 - 768 = 52*64

#define NCH1 64                     // 64-wide k-chunks in GEMM1 (k over 4096)
#define NCH2 52                     // k-chunks in GEMM2 (k over 3328)

typedef unsigned short ushort_t;
using bf16x8 = __attribute__((ext_vector_type(8))) __bf16;
using f32x4  = __attribute__((ext_vector_type(4))) float;

__device__ __forceinline__ ushort_t f2bf(float f) {
    union { float f; unsigned int u; } v; v.f = f;
    unsigned int r = v.u + 0x7fffu + ((v.u >> 16) & 1u);   // RNE
    return (ushort_t)(r >> 16);
}
__device__ __forceinline__ float bf2f(ushort_t h) {
    union { unsigned int u; float f; } v; v.u = ((unsigned int)h) << 16;
    return v.f;
}

// fragment-order index of element (r, c) inside a 64x64 tile-chunk
__device__ __forceinline__ int pkidx(int r, int c) {
    const int s = ((r >> 4) << 1) | ((c >> 5) & 1);
    return s * 512 + (r & 15) * 8 + (((c >> 3) & 3) << 7) + (c & 7);
}

__device__ __forceinline__ void async_copy16(const ushort_t* g, ushort_t* l) {
    __builtin_amdgcn_global_load_lds(
        (__attribute__((address_space(1))) void*)(g),
        (__attribute__((address_space(3))) void*)(l),
        16, 0, 0);
}

// --- pack w -> w_pk [52 ntile][64 chunk][4096]  (B of GEMM1: rows 768..4095)
//            -> wt_pk [52 ntile][52 chunk][4096] (B of GEMM2: w^T, live range)
__global__ __launch_bounds__(256) void pack_w(const float* __restrict__ w,
                                              ushort_t* __restrict__ wpk,
                                              ushort_t* __restrict__ wtpk) {
    __shared__ float tile[64][68];
    const int tid = threadIdx.x;
    const int bid = blockIdx.x;
    int row0, col0; ushort_t* dst; bool tr;
    if (bid < 52 * 64) {
        tr   = false;
        dst  = wpk + (size_t)bid * 4096;
        row0 = N0 + (bid >> 6) * 64;      // B-row (n) block
        col0 = (bid & 63) * 64;           // k block
    } else {
        const int b2 = bid - 52 * 64;
        tr   = true;
        dst  = wtpk + (size_t)b2 * 4096;
        const int ntile = b2 / 52, chunk = b2 - ntile * 52;
        row0 = N0 + chunk * 64;           // w-row  = k block (live)
        col0 = N0 + ntile * 64;           // w-col  = n block (live)
    }
    const int rr = tid >> 2, c0 = (tid & 3) * 16;
    const float* src = w + (size_t)(row0 + rr) * N_DIM + col0 + c0;
#pragma unroll
    for (int i = 0; i < 16; i += 4)
        *(float4*)&tile[rr][c0 + i] = *(const float4*)(src + i);
    __syncthreads();
    ushort_t loc[16];
#pragma unroll
    for (int i = 0; i < 16; ++i) {
        const int p = tid * 16 + i;
        const int s = p >> 9, e = p & 511;
        const int r = ((s >> 1) << 4) | ((e >> 3) & 15);
        const int c = ((s & 1) << 5) | (((e >> 7) & 3) << 3) | (e & 7);
        loc[i] = f2bf(tr ? tile[c][r] : tile[r][c]);
    }
    *(uint4*)&dst[tid * 16]     = *(uint4*)&loc[0];
    *(uint4*)&dst[tid * 16 + 8] = *(uint4*)&loc[8];
}

// --- init: x -> d_out (row-major) and t_pk [4 mtile][64 chunk][4096] --------
__global__ __launch_bounds__(256) void pack_t_init(const float* __restrict__ xin,
                                                   float* __restrict__ xout,
                                                   ushort_t* __restrict__ tpk) {
    __shared__ float tile[64][68];
    const int tid  = threadIdx.x;
    const int bid  = blockIdx.x;          // mtile*64 + chunk
    const int row0 = (bid >> 6) * 64;
    const int col0 = (bid & 63) * 64;
    const int rr = tid >> 2, c0 = (tid & 3) * 16;
    const size_t sidx = (size_t)(row0 + rr) * N_DIM + col0 + c0;
#pragma unroll
    for (int i = 0; i < 16; i += 4) {
        float4 v = *(const float4*)(xin + sidx + i);
        *(float4*)(xout + sidx + i) = v;
        tile[rr][c0 + i + 0] = tanhf(v.x);
        tile[rr][c0 + i + 1] = tanhf(v.y);
        tile[rr][c0 + i + 2] = tanhf(v.z);
        tile[rr][c0 + i + 3] = tanhf(v.w);
    }
    __syncthreads();
    ushort_t loc[16];
    ushort_t* dst = tpk + (size_t)bid * 4096;
#pragma unroll
    for (int i = 0; i < 16; ++i) {
        const int p = tid * 16 + i;
        const int s = p >> 9, e = p & 511;
        const int r = ((s >> 1) << 4) | ((e >> 3) & 15);
        const int c = ((s & 1) << 5) | (((e >> 7) & 3) << 3) | (e & 7);
        loc[i] = f2bf(tile[r][c]);
    }
    *(uint4*)&dst[tid * 16]     = *(uint4*)&loc[0];
    *(uint4*)&dst[tid * 16 + 8] = *(uint4*)&loc[8];
}

// --- cvt1 (after GEMM1): mu = sum partials; e -> e_pk (packed, GEMM2 A) -----
__global__ void cvt1(const float* __restrict__ xbuf,
                     const ushort_t* __restrict__ part,
                     ushort_t* __restrict__ epk,
                     const int* __restrict__ mask, int nz) {
    const int b  = blockIdx.y;
    const int nl = blockIdx.x * 256 + threadIdx.x;
    const size_t il = (size_t)b * N_LIVE + nl;
    float mu = 0.0f;
    for (int z = 0; z < nz; ++z)
        mu += bf2f(part[(size_t)z * (B_DIM * N_LIVE) + il]);
    const float x = xbuf[(size_t)b * N_DIM + N0 + nl];
    const float e = (x - mu) * (float)mask[N0 + nl];
    epk[((size_t)((b >> 6) * NCH2 + (nl >> 6))) * 4096 + pkidx(b & 63, nl & 63)]
        = f2bf(e);
}

// --- cvt2 (after GEMM2): g = sum partials; x update; refresh t_pk -----------
__global__ void cvt2(float* __restrict__ xbuf,
                     const ushort_t* __restrict__ part,
                     const ushort_t* __restrict__ epk,
                     ushort_t* __restrict__ tpk,
                     const int* __restrict__ mask, int nz) {
    const int b  = blockIdx.y;
    const int nl = blockIdx.x * 256 + threadIdx.x;
    const size_t ix = (size_t)b * N_DIM + N0 + nl;
    float g = 0.0f;
    for (int z = 0; z < nz; ++z)
        g += bf2f(part[(size_t)z * (B_DIM * N_LIVE) + (size_t)b * N_LIVE + nl]);
    const float x  = xbuf[ix];
    const float th = tanhf(x);
    const float e  = bf2f(epk[((size_t)((b >> 6) * NCH2 + (nl >> 6))) * 4096
                              + pkidx(b & 63, nl & 63)]);
    const float m  = (float)mask[N0 + nl];
    const float xn = x - LR_X * m * (e - (1.0f - th * th) * g);
    xbuf[ix] = xn;
    const int k = N0 + nl;
    tpk[((size_t)((b >> 6) * NCH1 + (k >> 6))) * 4096 + pkidx(b & 63, k & 63)]
        = f2bf(tanhf(xn));
}

// --- split-K GEMM, 128x128 tile, BK=64 (full chunk/iter), 64 KB LDS ---------
// grid (26, 2, Z). Z=8: GEMM1 8 chunks/slice, GEMM2 7/6 (uneven via rem).
// A = packed mtiles {2y, 2y+1}, B = packed ntiles {2x, 2x+1}. Per iter each
// wave stages 4 A + 4 B sub-tiles (8 x 1KB lane-linear DMAs) and computes
// 32 MFMA (full 64x64 output quadrant, both k-halves).
template <int NCH>
__global__ __launch_bounds__(256) void gemm_split(
    const ushort_t* __restrict__ Apk,
    const ushort_t* __restrict__ Bpk,
    ushort_t* __restrict__ part, int Z) {
    __shared__ __align__(16) ushort_t As[2][16 * 512];  // 2 x 16 KB
    __shared__ __align__(16) ushort_t Bs[2][16 * 512];  // 2 x 16 KB

    const int tid    = threadIdx.x;
    const int lane   = tid & 63;
    const int wid    = tid >> 6;       // 0..3
    const int wave_m = wid >> 1;       // 0..1  (64-row half of 128)
    const int wave_n = wid & 1;        // 0..1  (64-col half of 128)
    const int ntile2 = blockIdx.x;     // covers ntiles {2x, 2x+1}
    const int mtile2 = blockIdx.y;     // covers mtiles {2y, 2y+1}
    const int z      = blockIdx.z;

    const int per = NCH / Z, rem = NCH % Z;
    const int kcount = per + (z < rem ? 1 : 0);
    const int kstart = z * per + (z < rem ? z : rem);
    ushort_t* pout = part + (size_t)z * (B_DIM * N_LIVE);

    const int l15  = lane & 15;
    const int quad = lane >> 4;        // 0..3

    const ushort_t* Ab0 = Apk + ((size_t)(mtile2 * 2) * NCH + kstart) * 4096;
    const ushort_t* Ab1 = Ab0 + (size_t)NCH * 4096;
    const ushort_t* Bb0 = Bpk + ((size_t)(ntile2 * 2) * NCH + kstart) * 4096;
    const ushort_t* Bb1 = Bb0 + (size_t)NCH * 4096;

    auto stage = [&](int buf, int kt) {
        const size_t co = (size_t)kt * 4096;
#pragma unroll
        for (int u = 0; u < 4; ++u) {
            const int st  = wid * 4 + u;             // 0..15 = p*8 + s
            const int so  = (st & 7) * 512 + lane * 8;
            const int dof = st * 512 + lane * 8;
            async_copy16((st < 8 ? Ab0 : Ab1) + co + so, &As[buf][dof]);
            async_copy16((st < 8 ? Bb0 : Bb1) + co + so, &Bs[buf][dof]);
        }
    };

    f32x4 acc[4][4] = {};

    auto compute = [&](int buf) {
#pragma unroll
        for (int ks = 0; ks < 2; ++ks) {
            bf16x8 a[4], b[4];
#pragma unroll
            for (int i = 0; i < 4; ++i)
                a[i] = *(const bf16x8*)(
                    &As[buf][(wave_m * 8 + i * 2 + ks) * 512 + lane * 8]);
#pragma unroll
            for (int j = 0; j < 4; ++j)
                b[j] = *(const bf16x8*)(
                    &Bs[buf][(wave_n * 8 + j * 2 + ks) * 512 + lane * 8]);
#pragma unroll
            for (int i = 0; i < 4; ++i)
#pragma unroll
                for (int j = 0; j < 4; ++j)
                    acc[i][j] = __builtin_amdgcn_mfma_f32_16x16x32_bf16(
                        a[i], b[j], acc[i][j], 0, 0, 0);
        }
    };

    stage(0, 0);
    __syncthreads();
    for (int kt = 0; kt < kcount; ++kt) {
        if (kt + 1 < kcount) stage((kt + 1) & 1, kt + 1);
        compute(kt & 1);
        __syncthreads();
    }

    // Epilogue: bf16 partial stores. C/D: col = lane&15, row = quad*4+reg
#pragma unroll
    for (int j = 0; j < 4; ++j) {
        const int nl = ntile2 * 128 + wave_n * 64 + j * 16 + l15;
#pragma unroll
        for (int i = 0; i < 4; ++i) {
#pragma unroll
            for (int r = 0; r < 4; ++r) {
                const int m = mtile2 * 128 + wave_m * 64 + i * 16 + quad * 4 + r;
                pout[(size_t)m * N_LIVE + nl] = f2bf(acc[i][j][r]);
            }
        }
    }
}

extern "C" void kernel_launch(void* const* d_in, const int* in_sizes, int n_in,
                              void* d_out, int out_size, void* d_ws, size_t ws_size,
                              hipStream_t stream) {
    const float* x_in  = (const float*)d_in[0];
    const float* w_in  = (const float*)d_in[1];
    const int*   mask  = (const int*)d_in[2];
    float*       xbuf  = (float*)d_out;          // state lives in d_out

    uint8_t* ws = (uint8_t*)d_ws;
    ushort_t* w_pk  = (ushort_t*)(ws);                   // 52*64*4096*2 = 27,262,976
    ushort_t* wt_pk = (ushort_t*)(ws + 27262976);        // 52*52*4096*2 = 22,151,168
    ushort_t* t_pk  = (ushort_t*)(ws + 49414144);        //  4*64*4096*2 =  2,097,152
    ushort_t* e_pk  = (ushort_t*)(ws + 51511296);        //  4*52*4096*2 =  1,703,936
    ushort_t* part  = (ushort_t*)(ws + 53215232);        // Z*256*3328*2

    // Z=8 end @ 66,846,720 bytes (proven in-bounds by rounds 10-12).
    const int Z = (ws_size >= (size_t)66846720) ? 8 : 4;

    pack_w<<<dim3(52 * 64 + 52 * 52), 256, 0, stream>>>(w_in, w_pk, wt_pk);
    pack_t_init<<<dim3(4 * 64), 256, 0, stream>>>(x_in, xbuf, t_pk);

    const dim3 ggrid(N_LIVE / 128, B_DIM / 128, Z);
    const dim3 cgrid(N_LIVE / 256, B_DIM);
    for (int t = 0; t < T_STEPS; ++t) {
        // GEMM1: part[z] = mu partial ; A = t_pk (64 chunks), B = w_pk
        gemm_split<NCH1><<<ggrid, 256, 0, stream>>>(t_pk, w_pk, part, Z);
        cvt1<<<cgrid, 256, 0, stream>>>(xbuf, part, e_pk, mask, Z);
        // GEMM2: part[z] = g partial ; A = e_pk (52 chunks), B = wt_pk
        gemm_split<NCH2><<<ggrid, 256, 0, stream>>>(e_pk, wt_pk, part, Z);
        cvt2<<<cgrid, 256, 0, stream>>>(xbuf, part, e_pk, t_pk, mask, Z);
    }
}